// Round 5
// baseline (442.635 us; speedup 1.0000x reference)
//
#include <hip/hip_runtime.h>

// LSTM B=8192,T=256,I=1,H=50 via MFMA, operand-swapped + two-group pipeline.
// Per block: 32 batches as two groups of 16 (G0,G1), 4 waves, 256 blocks = 1/CU.
// Per step per group: D[208x16] = W[208x64] x h[64x16]; rows = unit*4+gate
// (52 units: 50 real + x-col + bias-col), cols = batches. C/D layout puts the
// 4 gates of one (batch,unit) in one lane's 4 acc regs -> elementwise in-register.
// Pipeline: MFMA(G0) -> MFMA(G1) -> trans(G0) -> trans(G1) -> one barrier.
// G1's MFMAs + G0's trans hide each other's latency (separate pipes, m114).
// h carried as bf16 hi+lo planes (3-product MFMA ~ fp32, verified R3/R4).

#define NTH 256
#define TST 256
#define MB 32
#define NBLK 256         // 8192/32
#define HR 72            // h row stride in shorts (16B-aligned frag reads; 2-way bank alias = free)
#define HSZ (MB * HR)    // 2304 shorts per buffer

typedef __attribute__((ext_vector_type(8))) short short8;
typedef __attribute__((ext_vector_type(4))) float float4v;

__device__ __forceinline__ unsigned short bfhi(float v) {
    return (unsigned short)(__float_as_uint(v) >> 16);  // truncate; lo catches rest
}
__device__ __forceinline__ float bfup(unsigned short u) {
    return __uint_as_float(((unsigned int)u) << 16);
}
__device__ __forceinline__ float sigm(float v) {
    return __builtin_amdgcn_rcpf(1.0f + __expf(-v));
}
__device__ __forceinline__ float tanh_fast(float v) {
    float e = __expf(2.0f * v);
    return 1.0f - 2.0f * __builtin_amdgcn_rcpf(e + 1.0f);
}

__global__ __launch_bounds__(NTH, 1) void lstm_mfma(
    const float* __restrict__ x,      // [8192][256]
    const float* __restrict__ W_ih,   // [200]
    const float* __restrict__ W_hh,   // [200][50]
    const float* __restrict__ b_ih,   // [200]
    const float* __restrict__ b_hh,   // [200]
    const float* __restrict__ W_lin,  // [50]
    const float* __restrict__ b_lin,  // [1]
    float* __restrict__ out)          // [8192]
{
    __shared__ __align__(16) unsigned short Hhi[2 * HSZ];  // [buf][b*HR + k]
    __shared__ __align__(16) unsigned short Hlo[2 * HSZ];
    __shared__ __align__(16) float xs[2 * 64 * 33];        // double-buffered x chunks

    const int tid  = threadIdx.x;
    const int wv   = tid >> 6;
    const int ln   = tid & 63;
    const int lrow = ln & 15;   // batch-in-group / A-row
    const int quad = ln >> 4;
    const int bbase = (int)blockIdx.x * MB;

    // ---- W-operand fragments, slots s=0..2 -> tile T=wv+4s, slot 3 -> T=12.
    // Row gr=T*16+lrow -> unit j=gr>>2, gate g=gr&3, W row = g*50+j.
    // k = q2*32 + quad*8 + i; k=50 -> W_ih, k=51 -> bias; pad rows zero.
    short8 wh[4][2], wl[4][2];
    #pragma unroll
    for (int s = 0; s < 4; ++s) {
        const int T  = (s < 3) ? (wv + 4 * s) : 12;
        const int gr = T * 16 + lrow;
        const int j  = gr >> 2, g = gr & 3;
        const int row = g * 50 + j;   // only dereferenced when j < 50
        #pragma unroll
        for (int q2 = 0; q2 < 2; ++q2) {
            short8 h8, l8;
            #pragma unroll
            for (int i = 0; i < 8; ++i) {
                const int k = q2 * 32 + quad * 8 + i;
                float V = 0.0f;
                if (j < 50) {
                    if (k < 50)       V = W_hh[row * 50 + k];
                    else if (k == 50) V = W_ih[row];
                    else if (k == 51) V = b_ih[row] + b_hh[row];
                }
                unsigned short hb = bfhi(V);
                h8[i] = (short)hb;
                l8[i] = (short)bfhi(V - bfup(hb));
            }
            wh[s][q2] = h8;
            wl[s][q2] = l8;
        }
    }

    // ---- zero h planes; slots k=50 (x(0), buf0) and k=51 (1.0, BOTH bufs)
    for (int i = tid; i < 2 * HSZ / 2; i += NTH) {
        ((unsigned int*)Hhi)[i] = 0u;
        ((unsigned int*)Hlo)[i] = 0u;
    }
    __syncthreads();
    if (tid < MB) {
        float xv = x[(bbase + tid) * TST + 0];
        unsigned short xh = bfhi(xv);
        Hhi[tid * HR + 50] = xh;
        Hlo[tid * HR + 50] = bfhi(xv - bfup(xh));
        Hhi[tid * HR + 51] = 0x3F80;        // bf16(1.0), never rewritten
        Hhi[HSZ + tid * HR + 51] = 0x3F80;
    }
    {   // stage x chunk 0 (t=0..63): 64 rows x 32 batches, 8 floats/thread
        const int b = tid & 31, i0 = (tid >> 5) * 8;
        const float* xp = &x[(bbase + b) * TST + i0];
        const float4 a = *(const float4*)xp;
        const float4 c = *(const float4*)(xp + 4);
        xs[(i0 + 0) * 33 + b] = a.x; xs[(i0 + 1) * 33 + b] = a.y;
        xs[(i0 + 2) * 33 + b] = a.z; xs[(i0 + 3) * 33 + b] = a.w;
        xs[(i0 + 4) * 33 + b] = c.x; xs[(i0 + 5) * 33 + b] = c.y;
        xs[(i0 + 6) * 33 + b] = c.z; xs[(i0 + 7) * 33 + b] = c.w;
    }
    float cst0[4] = {0.f, 0.f, 0.f, 0.f};
    float cst1[4] = {0.f, 0.f, 0.f, 0.f};
    __syncthreads();

    for (int t = 0; t < TST; ++t) {
        const int buf  = (t & 1) * HSZ;
        const int nbuf = HSZ - buf;

        // restage NEXT x chunk mid-way (no same-step consumer -> race-free;
        // end-of-step barrier publishes it well before first use)
        if (((t & 63) == 32) && t < 192) {
            const int b = tid & 31, i0 = (tid >> 5) * 8;
            const float* xp = &x[(bbase + b) * TST + (t & ~63) + 64 + i0];
            const float4 a = *(const float4*)xp;
            const float4 c = *(const float4*)(xp + 4);
            const int co = ((((t >> 6) & 1) ^ 1) * 64) * 33;
            xs[co + (i0 + 0) * 33 + b] = a.x; xs[co + (i0 + 1) * 33 + b] = a.y;
            xs[co + (i0 + 2) * 33 + b] = a.z; xs[co + (i0 + 3) * 33 + b] = a.w;
            xs[co + (i0 + 4) * 33 + b] = c.x; xs[co + (i0 + 5) * 33 + b] = c.y;
            xs[co + (i0 + 6) * 33 + b] = c.z; xs[co + (i0 + 7) * 33 + b] = c.w;
        }

        // ---- h fragments for both groups (8 x ds_read_b128)
        const int ha0 = buf + lrow * HR + quad * 8;
        const int ha1 = buf + (16 + lrow) * HR + quad * 8;
        const short8 g0h0 = *(const short8*)&Hhi[ha0];
        const short8 g0h1 = *(const short8*)&Hhi[ha0 + 32];
        const short8 g0l0 = *(const short8*)&Hlo[ha0];
        const short8 g0l1 = *(const short8*)&Hlo[ha0 + 32];
        const short8 g1h0 = *(const short8*)&Hhi[ha1];
        const short8 g1h1 = *(const short8*)&Hhi[ha1 + 32];
        const short8 g1l0 = *(const short8*)&Hlo[ha1];
        const short8 g1l1 = *(const short8*)&Hlo[ha1 + 32];

        float4v acc0[4], acc1[4];

        // ---- MFMA phase, G0 (slot 3 only on wave 0)
        #pragma unroll
        for (int s = 0; s < 4; ++s) {
            float4v a4 = {0.f, 0.f, 0.f, 0.f};
            if (!(s == 3 && wv != 0)) {
                a4 = __builtin_amdgcn_mfma_f32_16x16x32_bf16(wh[s][0], g0h0, a4, 0, 0, 0);
                a4 = __builtin_amdgcn_mfma_f32_16x16x32_bf16(wh[s][1], g0h1, a4, 0, 0, 0);
                a4 = __builtin_amdgcn_mfma_f32_16x16x32_bf16(wl[s][0], g0h0, a4, 0, 0, 0);
                a4 = __builtin_amdgcn_mfma_f32_16x16x32_bf16(wl[s][1], g0h1, a4, 0, 0, 0);
                a4 = __builtin_amdgcn_mfma_f32_16x16x32_bf16(wh[s][0], g0l0, a4, 0, 0, 0);
                a4 = __builtin_amdgcn_mfma_f32_16x16x32_bf16(wh[s][1], g0l1, a4, 0, 0, 0);
            }
            acc0[s] = a4;
        }
        // ---- MFMA phase, G1 (slot 3 only on wave 3)
        #pragma unroll
        for (int s = 0; s < 4; ++s) {
            float4v a4 = {0.f, 0.f, 0.f, 0.f};
            if (!(s == 3 && wv != 3)) {
                a4 = __builtin_amdgcn_mfma_f32_16x16x32_bf16(wh[s][0], g1h0, a4, 0, 0, 0);
                a4 = __builtin_amdgcn_mfma_f32_16x16x32_bf16(wh[s][1], g1h1, a4, 0, 0, 0);
                a4 = __builtin_amdgcn_mfma_f32_16x16x32_bf16(wl[s][0], g1h0, a4, 0, 0, 0);
                a4 = __builtin_amdgcn_mfma_f32_16x16x32_bf16(wl[s][1], g1h1, a4, 0, 0, 0);
                a4 = __builtin_amdgcn_mfma_f32_16x16x32_bf16(wh[s][0], g1l0, a4, 0, 0, 0);
                a4 = __builtin_amdgcn_mfma_f32_16x16x32_bf16(wh[s][1], g1l1, a4, 0, 0, 0);
            }
            acc1[s] = a4;
        }

        const int xrow = (((t + 1) >> 6) & 1) * 64 + ((t + 1) & 63);

        // ---- trans + h write, G0 (overlaps G1's in-flight MFMAs)
        #pragma unroll
        for (int s = 0; s < 4; ++s) {
            if (s == 3 && wv != 0) continue;
            const int T = (s < 3) ? (wv + 4 * s) : 12;
            float i_ = sigm(acc0[s][0]);
            float f_ = sigm(acc0[s][1]);
            float g_ = tanh_fast(acc0[s][2]);
            float o_ = sigm(acc0[s][3]);
            float cn = f_ * cst0[s] + i_ * g_;
            cst0[s] = cn;
            float hn = o_ * tanh_fast(cn);
            bool wr = true;
            if (T == 12) {
                if (quad == 2)      hn = xs[xrow * 33 + lrow];   // k=50: x(t+1)
                else if (quad == 3) wr = false;                  // k=51: keep 1.0
            }
            if (wr) {
                const int j = T * 4 + quad;
                unsigned short hh = bfhi(hn);
                Hhi[nbuf + lrow * HR + j] = hh;
                Hlo[nbuf + lrow * HR + j] = bfhi(hn - bfup(hh));
            }
        }
        // ---- trans + h write, G1
        #pragma unroll
        for (int s = 0; s < 4; ++s) {
            if (s == 3 && wv != 3) continue;
            const int T = (s < 3) ? (wv + 4 * s) : 12;
            float i_ = sigm(acc1[s][0]);
            float f_ = sigm(acc1[s][1]);
            float g_ = tanh_fast(acc1[s][2]);
            float o_ = sigm(acc1[s][3]);
            float cn = f_ * cst1[s] + i_ * g_;
            cst1[s] = cn;
            float hn = o_ * tanh_fast(cn);
            bool wr = true;
            if (T == 12) {
                if (quad == 2)      hn = xs[xrow * 33 + 16 + lrow];
                else if (quad == 3) wr = false;
            }
            if (wr) {
                const int j = T * 4 + quad;
                unsigned short hh = bfhi(hn);
                Hhi[nbuf + (16 + lrow) * HR + j] = hh;
                Hlo[nbuf + (16 + lrow) * HR + j] = bfhi(hn - bfup(hh));
            }
        }
        __syncthreads();   // publish nbuf h (and staged x) for next step
    }

    // ---- epilogue: final h in buf 0 (t=255 wrote nbuf=0)
    if (tid < MB) {
        float s = b_lin[0];
        #pragma unroll 10
        for (int k = 0; k < 50; ++k) {
            float hk = bfup(Hhi[tid * HR + k]) + bfup(Hlo[tid * HR + k]);
            s += hk * W_lin[k];
        }
        out[bbase + tid] = s;
    }
}

extern "C" void kernel_launch(void* const* d_in, const int* in_sizes, int n_in,
                              void* d_out, int out_size, void* d_ws, size_t ws_size,
                              hipStream_t stream) {
    const float* x     = (const float*)d_in[0];
    const float* W_ih  = (const float*)d_in[1];
    const float* W_hh  = (const float*)d_in[2];
    const float* b_ih  = (const float*)d_in[3];
    const float* b_hh  = (const float*)d_in[4];
    const float* W_lin = (const float*)d_in[5];
    const float* b_lin = (const float*)d_in[6];
    float* out = (float*)d_out;

    lstm_mfma<<<dim3(NBLK), dim3(NTH), 0, stream>>>(
        x, W_ih, W_hh, b_ih, b_hh, W_lin, b_lin, out);
}